// Round 5
// baseline (1809.494 us; speedup 1.0000x reference)
//
#include <hip/hip_runtime.h>
#include <hip/hip_bf16.h>

#define T_LEN 200
#define F_IN 64
#define A_IN 128
#define H 100
#define H4 400
#define OUT_N 10
#define ROWS 8

typedef __attribute__((ext_vector_type(8))) short bf16x8;
typedef __attribute__((ext_vector_type(4))) float f32x4;

__device__ __forceinline__ unsigned short f2bf(float f) {
    union { float f; unsigned u; } v; v.f = f;
    unsigned r = v.u + 0x7FFFu + ((v.u >> 16) & 1u);
    return (unsigned short)(r >> 16);
}

// 2x f32 -> packed bf16 (RNE), single instruction
__device__ __forceinline__ unsigned cvtpk(float lo, float hi) {
    unsigned r;
    asm("v_cvt_pk_bf16_f32 %0, %1, %2" : "=v"(r) : "v"(lo), "v"(hi));
    return r;
}

__device__ __forceinline__ float sigm(float x) {
    return 1.0f / (1.0f + __expf(-x));
}

// h fragment slot for (batch b, hidden j): B-frag col=lane&15=b, k=lg*8+i
#define HOFF(b, j) ((((j) >> 5) * 64 + ((b) + 16 * (((j) >> 3) & 3))) * 8 + ((j) & 7))

extern "C" __global__ void __launch_bounds__(512, 4)
traj_kernel(const float* __restrict__ attrs, const float* __restrict__ seq,
            const float* __restrict__ Wd, const float* __restrict__ bd,
            const float* __restrict__ Wk, const float* __restrict__ Wr,
            const float* __restrict__ bl, const float* __restrict__ W1,
            const float* __restrict__ b1, const float* __restrict__ W2,
            const float* __restrict__ b2, const float* __restrict__ Wc,
            const float* __restrict__ bc, float* __restrict__ out)
{
    // LDS map (bytes), total 22400:
    //   [0, 8192)       hl   ushort[2][2048]  h bf16 B-frag double buffer
    //   [16000, 22400)  h32  float[16][100]   final h fp32 (rows 8..15 absorb garbage lanes)
    // epilogue aliases (loop-dead regions, all < 16000):
    //   att [8][136]@0, catb [8][204]@4352, x1b [8][100]@10880,
    //   x2b [8][50]@14080, lgb [8][10]@15680
    __shared__ __align__(16) char smem[22400];
    unsigned short* hl = (unsigned short*)smem;
    float* h32 = (float*)(smem + 16000);

    const int tid = threadIdx.x;
    const int lane = tid & 63;
    const int w = tid >> 6;
    const int ln15 = lane & 15;
    const int lg = lane >> 4;
    const int b0 = blockIdx.x * ROWS;

    // output-dim tiles (Z^T rows): waves 0..6 own {3w..3w+2}; wave 7 owns {21..24}
    const int nt0 = 3 * w;
    const int ntc = (w == 7) ? 4 : 3;
    const bool w7 = (w == 7);

    // ---- one-time weight A-fragment packing, with gate-interleaved column perm ----
    // A-frag (16x16x32): lane holds row m = lane&15, k = (lane>>4)*8 + i.
    // Permuted row p = tile*16 + m maps to original column c = (tile*4 + (m>>2)) + 100*(m&3),
    // so D rows lg*4+r of a lane are gates r=i,f,g,o of hidden j = tile*4+lg.
    bf16x8 wkf[4][2];
    bf16x8 wrf[4][4];
    f32x4 blf[4];
    const int rw = ln15 & 3;          // gate index of this lane's A rows
    const int qr = ln15 >> 2;         // j sub-index
#pragma unroll
    for (int q = 0; q < 4; q++) {
        const bool v = (q < ntc);
        const int tile = nt0 + q;
        const int c = v ? (tile * 4 + qr) + 100 * rw : 0;
#pragma unroll
        for (int kt = 0; kt < 2; kt++) {
            bf16x8 f;
#pragma unroll
            for (int i = 0; i < 8; i++) {
                int k = kt * 32 + lg * 8 + i;
                f[i] = (short)f2bf(v ? Wk[k * H4 + c] : 0.0f);
            }
            wkf[q][kt] = f;
        }
#pragma unroll
        for (int kt = 0; kt < 4; kt++) {
            bf16x8 f;
#pragma unroll
            for (int i = 0; i < 8; i++) {
                int k = kt * 32 + lg * 8 + i;
                f[i] = (short)f2bf((v && k < H) ? Wr[k * H4 + c] : 0.0f);
            }
            wrf[q][kt] = f;
        }
        int j = tile * 4 + lg;
        if (v) blf[q] = (f32x4){ bl[j], bl[H + j], bl[2 * H + j], bl[3 * H + j] };
        else   blf[q] = (f32x4){ 0.f, 0.f, 0.f, 0.f };
    }

    // gate destinations: batch b = ln15 (8..15 are confined garbage), hidden j_q
    int hoq[4], h32q[4];
#pragma unroll
    for (int q = 0; q < 4; q++) {
        int j = (nt0 + q) * 4 + lg;
        if (j > 99) j = 99;  // inactive q only
        hoq[q] = HOFF(ln15, j);
        h32q[q] = ln15 * H + j;
    }
    float cr0 = 0.f, cr1 = 0.f, cr2 = 0.f, cr3 = 0.f;

    // zero both h buffers (padding k>=100 stays zero forever)
    for (int i = tid; i < 4096; i += 512) hl[i] = 0;

    // ---- seq staging: lane = batch row ln15 (clamped), feats lg*8..+7, 32+lg*8..+7
    int brow = b0 + ln15; if (brow > 4095) brow = 4095;
    const float* sp = seq + (size_t)brow * (T_LEN * F_IN) + lg * 8;
    f32x4 s0 = *(const f32x4*)(sp);
    f32x4 s1 = *(const f32x4*)(sp + 4);
    f32x4 s2 = *(const f32x4*)(sp + 32);
    f32x4 s3 = *(const f32x4*)(sp + 36);
    sp += F_IN;

    // prologue: accX = bias + x(0)@Wk^T
    f32x4 accX[4];
    {
        union { unsigned u[4]; bf16x8 v; } ua, ub;
        ua.u[0] = cvtpk(s0[0], s0[1]); ua.u[1] = cvtpk(s0[2], s0[3]);
        ua.u[2] = cvtpk(s1[0], s1[1]); ua.u[3] = cvtpk(s1[2], s1[3]);
        ub.u[0] = cvtpk(s2[0], s2[1]); ub.u[1] = cvtpk(s2[2], s2[3]);
        ub.u[2] = cvtpk(s3[0], s3[1]); ub.u[3] = cvtpk(s3[2], s3[3]);
        bf16x8 a0 = ua.v, a1 = ub.v;
#pragma unroll
        for (int q = 0; q < 3; q++) {
            f32x4 x = __builtin_amdgcn_mfma_f32_16x16x32_bf16(wkf[q][0], a0, blf[q], 0, 0, 0);
            accX[q] = __builtin_amdgcn_mfma_f32_16x16x32_bf16(wkf[q][1], a1, x, 0, 0, 0);
        }
        if (w7) {
            f32x4 x = __builtin_amdgcn_mfma_f32_16x16x32_bf16(wkf[3][0], a0, blf[3], 0, 0, 0);
            accX[3] = __builtin_amdgcn_mfma_f32_16x16x32_bf16(wkf[3][1], a1, x, 0, 0, 0);
        }
    }
    // issue load of x(1)
    s0 = *(const f32x4*)(sp);
    s1 = *(const f32x4*)(sp + 4);
    s2 = *(const f32x4*)(sp + 32);
    s3 = *(const f32x4*)(sp + 36);
    sp += F_IN;

    __syncthreads();   // hl zeros visible

#pragma unroll 2
    for (int t = 0; t < T_LEN; t++) {
        const bool notlast = (t < T_LEN - 1);
        const bool last = !notlast;

        // ---- read h(t-1) B-frags from buf[t&1] ----
        const unsigned short* hp = hl + ((t & 1) << 11) + lane * 8;
        bf16x8 hf0 = *(const bf16x8*)(hp);
        bf16x8 hf1 = *(const bf16x8*)(hp + 512);
        bf16x8 hf2 = *(const bf16x8*)(hp + 1024);
        bf16x8 hf3 = *(const bf16x8*)(hp + 1536);

        // cvt x(t+1) (overlaps h-frag read latency)
        bf16x8 a0n = {}, a1n = {};
        if (notlast) {
            union { unsigned u[4]; bf16x8 v; } ua, ub;
            ua.u[0] = cvtpk(s0[0], s0[1]); ua.u[1] = cvtpk(s0[2], s0[3]);
            ua.u[2] = cvtpk(s1[0], s1[1]); ua.u[3] = cvtpk(s1[2], s1[3]);
            ub.u[0] = cvtpk(s2[0], s2[1]); ub.u[1] = cvtpk(s2[2], s2[3]);
            ub.u[2] = cvtpk(s3[0], s3[1]); ub.u[3] = cvtpk(s3[2], s3[3]);
            a0n = ua.v; a1n = ub.v;
        }

        // ---- rr = accX + h(t-1)@Wr^T : per-lane gate quads land in rr[q] ----
        f32x4 rr[4];
        __builtin_amdgcn_s_setprio(1);
#pragma unroll
        for (int q = 0; q < 3; q++)
            rr[q] = __builtin_amdgcn_mfma_f32_16x16x32_bf16(wrf[q][0], hf0, accX[q], 0, 0, 0);
        if (w7)
            rr[3] = __builtin_amdgcn_mfma_f32_16x16x32_bf16(wrf[3][0], hf0, accX[3], 0, 0, 0);
#pragma unroll
        for (int q = 0; q < 3; q++)
            rr[q] = __builtin_amdgcn_mfma_f32_16x16x32_bf16(wrf[q][1], hf1, rr[q], 0, 0, 0);
        if (w7)
            rr[3] = __builtin_amdgcn_mfma_f32_16x16x32_bf16(wrf[3][1], hf1, rr[3], 0, 0, 0);
#pragma unroll
        for (int q = 0; q < 3; q++)
            rr[q] = __builtin_amdgcn_mfma_f32_16x16x32_bf16(wrf[q][2], hf2, rr[q], 0, 0, 0);
        if (w7)
            rr[3] = __builtin_amdgcn_mfma_f32_16x16x32_bf16(wrf[3][2], hf2, rr[3], 0, 0, 0);
#pragma unroll
        for (int q = 0; q < 3; q++)
            rr[q] = __builtin_amdgcn_mfma_f32_16x16x32_bf16(wrf[q][3], hf3, rr[q], 0, 0, 0);
        if (w7)
            rr[3] = __builtin_amdgcn_mfma_f32_16x16x32_bf16(wrf[3][3], hf3, rr[3], 0, 0, 0);
        __builtin_amdgcn_s_setprio(0);

        // prefetch x(t+2)
        if (t < T_LEN - 2) {
            s0 = *(const f32x4*)(sp);
            s1 = *(const f32x4*)(sp + 4);
            s2 = *(const f32x4*)(sp + 32);
            s3 = *(const f32x4*)(sp + 36);
            sp += F_IN;
        }

        // ---- gates entirely in registers; write h(t) bf16 to buf[(t+1)&1] ----
        unsigned short* hwp = hl + (((t + 1) & 1) << 11);

#define DOGATE(RRQ, CR, HO, HW) do {                                  \
            float _i = sigm(RRQ[0]), _f = sigm(RRQ[1]);               \
            float _g = fmaxf(RRQ[2], 0.0f), _o = sigm(RRQ[3]);        \
            CR = _f * CR + _i * _g;                                   \
            float _h = _o * fmaxf(CR, 0.0f);                          \
            hwp[HO] = (unsigned short)cvtpk(_h, _h);                  \
            if (last) h32[HW] = _h;                                   \
        } while (0)

        DOGATE(rr[0], cr0, hoq[0], h32q[0]);
        DOGATE(rr[1], cr1, hoq[1], h32q[1]);
        DOGATE(rr[2], cr2, hoq[2], h32q[2]);
        if (w7) DOGATE(rr[3], cr3, hoq[3], h32q[3]);

        // ---- accX = bias + x(t+1)@Wk^T (MFMA pipe, overlaps gate VALU) ----
        if (notlast) {
#pragma unroll
            for (int q = 0; q < 3; q++) {
                f32x4 x = __builtin_amdgcn_mfma_f32_16x16x32_bf16(wkf[q][0], a0n, blf[q], 0, 0, 0);
                accX[q] = __builtin_amdgcn_mfma_f32_16x16x32_bf16(wkf[q][1], a1n, x, 0, 0, 0);
            }
            if (w7) {
                f32x4 x = __builtin_amdgcn_mfma_f32_16x16x32_bf16(wkf[3][0], a0n, blf[3], 0, 0, 0);
                accX[3] = __builtin_amdgcn_mfma_f32_16x16x32_bf16(wkf[3][1], a1n, x, 0, 0, 0);
            }
        }

        __syncthreads();   // single barrier: h(t) visible; protects buf WAR
    }

    // ---- epilogue: fp32 dense chain + softmax (ROWS=8) ----
    float* att  = (float*)smem;            // [8][136]
    float* catb = (float*)(smem + 4352);   // [8][204]
    float* x1b  = (float*)(smem + 10880);  // [8][100]
    float* x2b  = (float*)(smem + 14080);  // [8][50]
    float* lgb  = (float*)(smem + 15680);  // [8][10]

    if (tid < 256) {
        f32x4 v = ((const f32x4*)(attrs + (size_t)b0 * A_IN))[tid];
        int row = tid >> 5, c4 = tid & 31;
        *(f32x4*)(att + row * 136 + c4 * 4) = v;
    }
    __syncthreads();

#pragma unroll
    for (int k = 0; k < 2; k++) {
        int e = tid + 512 * k;
        if (e < ROWS * H) {
            int b = e & 7, j = e >> 3;
            float s = bd[j];
            for (int kk = 0; kk < A_IN; kk++) s += att[b * 136 + kk] * Wd[kk * H + j];
            catb[b * 204 + j] = fmaxf(s, 0.0f);
            catb[b * 204 + H + j] = h32[b * H + j];
        }
    }
    __syncthreads();

#pragma unroll
    for (int k = 0; k < 2; k++) {
        int e = tid + 512 * k;
        if (e < ROWS * H) {
            int b = e & 7, j = e >> 3;
            float s = b1[j];
            for (int kk = 0; kk < 200; kk++) s += catb[b * 204 + kk] * W1[kk * H + j];
            x1b[b * H + j] = fmaxf(s, 0.0f);
        }
    }
    __syncthreads();

    if (tid < ROWS * 50) {
        int b = tid & 7, j = tid >> 3;
        float s = b2[j];
        for (int kk = 0; kk < H; kk++) s += x1b[b * H + kk] * W2[kk * 50 + j];
        x2b[b * 50 + j] = fmaxf(s, 0.0f);
    }
    __syncthreads();

    if (tid < ROWS * OUT_N) {
        int b = tid / OUT_N, o = tid % OUT_N;
        float s = bc[o];
        for (int kk = 0; kk < 50; kk++) s += x2b[b * 50 + kk] * Wc[kk * OUT_N + o];
        lgb[b * OUT_N + o] = s;
    }
    __syncthreads();

    if (tid < ROWS) {
        int b = tid;
        float m = -1e30f, v[10];
#pragma unroll
        for (int o = 0; o < 10; o++) { v[o] = lgb[b * 10 + o]; m = fmaxf(m, v[o]); }
        float ssum = 0.0f;
#pragma unroll
        for (int o = 0; o < 10; o++) { v[o] = __expf(v[o] - m); ssum += v[o]; }
        float inv = 1.0f / ssum;
#pragma unroll
        for (int o = 0; o < 10; o++) out[(size_t)(b0 + b) * 10 + o] = v[o] * inv;
    }
}

extern "C" void kernel_launch(void* const* d_in, const int* in_sizes, int n_in,
                              void* d_out, int out_size, void* d_ws, size_t ws_size,
                              hipStream_t stream) {
    const float* attrs = (const float*)d_in[0];
    const float* seq   = (const float*)d_in[1];
    const float* Wd    = (const float*)d_in[2];
    const float* bd    = (const float*)d_in[3];
    const float* Wk    = (const float*)d_in[4];
    const float* Wr    = (const float*)d_in[5];
    const float* bl    = (const float*)d_in[6];
    const float* W1    = (const float*)d_in[7];
    const float* b1    = (const float*)d_in[8];
    const float* W2    = (const float*)d_in[9];
    const float* b2    = (const float*)d_in[10];
    const float* Wc    = (const float*)d_in[11];
    const float* bc    = (const float*)d_in[12];
    float* out = (float*)d_out;

    hipLaunchKernelGGL(traj_kernel, dim3(512), dim3(512), 0, stream,
                       attrs, seq, Wd, bd, Wk, Wr, bl, W1, b1, W2, b2, Wc, bc, out);
}

// Round 6
// 441.484 us; speedup vs baseline: 4.0987x; 4.0987x over previous
//
#include <hip/hip_runtime.h>
#include <hip/hip_bf16.h>

#define T_LEN 200
#define F_IN 64
#define A_IN 128
#define H 100
#define H4 400
#define OUT_N 10
#define ROWS 8

typedef __attribute__((ext_vector_type(8))) short bf16x8;
typedef __attribute__((ext_vector_type(4))) float f32x4;

#define NLOG2E -1.4426950408889634f

__device__ __forceinline__ unsigned short f2bf(float f) {
    union { float f; unsigned u; } v; v.f = f;
    unsigned r = v.u + 0x7FFFu + ((v.u >> 16) & 1u);
    return (unsigned short)(r >> 16);
}

// 2x f32 -> packed bf16 (RNE), single instruction
__device__ __forceinline__ unsigned cvtpk(float lo, float hi) {
    unsigned r;
    asm("v_cvt_pk_bf16_f32 %0, %1, %2" : "=v"(r) : "v"(lo), "v"(hi));
    return r;
}

// sigmoid(z) where zp = -log2(e)*z was computed by the MFMA (weights pre-scaled):
// sigmoid = 1 / (1 + 2^zp).  v_exp + v_add + v_rcp, no division refinement.
__device__ __forceinline__ float sigm2(float zp) {
    return __builtin_amdgcn_rcpf(1.0f + __builtin_amdgcn_exp2f(zp));
}

// LDS-only barrier: do NOT drain vmcnt (seq prefetch stays in flight across steps)
__device__ __forceinline__ void lds_barrier() {
    asm volatile("s_waitcnt lgkmcnt(0)" ::: "memory");
    __builtin_amdgcn_s_barrier();
}

// h fragment slot for (batch b, hidden j): B-frag col=lane&15=b, k=lg*8+i
#define HOFF(b, j) ((((j) >> 5) * 64 + ((b) + 16 * (((j) >> 3) & 3))) * 8 + ((j) & 7))

extern "C" __global__ void __launch_bounds__(512, 2)
traj_kernel(const float* __restrict__ attrs, const float* __restrict__ seq,
            const float* __restrict__ Wd, const float* __restrict__ bd,
            const float* __restrict__ Wk, const float* __restrict__ Wr,
            const float* __restrict__ bl, const float* __restrict__ W1,
            const float* __restrict__ b1, const float* __restrict__ W2,
            const float* __restrict__ b2, const float* __restrict__ Wc,
            const float* __restrict__ bc, float* __restrict__ out)
{
    // LDS map (bytes), total 22400:
    //   [0, 8192)       hl   ushort[2][2048]  h bf16 B-frag double buffer
    //   [16000, 22400)  h32  float[16][100]   final h fp32 (rows 8..15 absorb garbage lanes)
    // epilogue aliases (loop-dead regions, all < 16000):
    //   att [8][136]@0, catb [8][204]@4352, x1b [8][100]@10880,
    //   x2b [8][50]@14080, lgb [8][10]@15680
    __shared__ __align__(16) char smem[22400];
    unsigned short* hl = (unsigned short*)smem;
    float* h32 = (float*)(smem + 16000);

    const int tid = threadIdx.x;
    const int lane = tid & 63;
    const int w = tid >> 6;
    const int ln15 = lane & 15;
    const int lg = lane >> 4;
    const int b0 = blockIdx.x * ROWS;

    // output-dim tiles (Z^T rows): waves 0..6 own {3w..3w+2}; wave 7 owns {21..24}
    const int nt0 = 3 * w;
    const int ntc = (w == 7) ? 4 : 3;
    const bool w7 = (w == 7);

    // ---- one-time weight A-fragment packing, gate-interleaved column perm ----
    // A-frag (16x16x32): lane holds row m = lane&15, k = (lane>>4)*8 + i.
    // Permuted row p = tile*16 + m  ->  original column c = (tile*4 + (m>>2)) + 100*(m&3),
    // so D rows lg*4+r of a lane are gates r=i,f,g,o of hidden j = tile*4+lg.
    // Gate rows i,f,o (m&3 != 2) are pre-scaled by -log2(e) for the exp2 sigmoid.
    bf16x8 wkf[4][2];
    bf16x8 wrf[4][4];
    f32x4 blf[4];
    const int rw = ln15 & 3;          // gate index of this lane's A rows
    const int qr = ln15 >> 2;         // j sub-index
    const float gsc = (rw == 2) ? 1.0f : NLOG2E;
#pragma unroll
    for (int q = 0; q < 4; q++) {
        const bool v = (q < ntc);
        const int tile = nt0 + q;
        const int c = v ? (tile * 4 + qr) + 100 * rw : 0;
#pragma unroll
        for (int kt = 0; kt < 2; kt++) {
            bf16x8 f;
#pragma unroll
            for (int i = 0; i < 8; i++) {
                int k = kt * 32 + lg * 8 + i;
                f[i] = (short)f2bf(v ? gsc * Wk[k * H4 + c] : 0.0f);
            }
            wkf[q][kt] = f;
        }
#pragma unroll
        for (int kt = 0; kt < 4; kt++) {
            bf16x8 f;
#pragma unroll
            for (int i = 0; i < 8; i++) {
                int k = kt * 32 + lg * 8 + i;
                f[i] = (short)f2bf((v && k < H) ? gsc * Wr[k * H4 + c] : 0.0f);
            }
            wrf[q][kt] = f;
        }
        int j = tile * 4 + lg;
        if (v) blf[q] = (f32x4){ NLOG2E * bl[j], NLOG2E * bl[H + j],
                                 bl[2 * H + j],  NLOG2E * bl[3 * H + j] };
        else   blf[q] = (f32x4){ 0.f, 0.f, 0.f, 0.f };
    }

    // gate destinations: batch b = ln15 (8..15 are confined garbage), hidden j_q
    int hoq[4], h32q[4];
#pragma unroll
    for (int q = 0; q < 4; q++) {
        int j = (nt0 + q) * 4 + lg;
        if (j > 99) j = 99;  // inactive q only
        hoq[q] = HOFF(ln15, j);
        h32q[q] = ln15 * H + j;
    }
    float cr0 = 0.f, cr1 = 0.f, cr2 = 0.f, cr3 = 0.f;

    // zero both h buffers (padding k>=100 stays zero forever)
    for (int i = tid; i < 4096; i += 512) hl[i] = 0;

    // ---- seq staging: lane = batch row ln15 (clamped), feats lg*8..+7, 32+lg*8..+7
    int brow = b0 + ln15; if (brow > 4095) brow = 4095;
    const float* sp = seq + (size_t)brow * (T_LEN * F_IN) + lg * 8;
    f32x4 s0 = *(const f32x4*)(sp);
    f32x4 s1 = *(const f32x4*)(sp + 4);
    f32x4 s2 = *(const f32x4*)(sp + 32);
    f32x4 s3 = *(const f32x4*)(sp + 36);
    sp += F_IN;

    // prologue: accX = bias + x(0)@Wk^T
    f32x4 accX[4];
    {
        union { unsigned u[4]; bf16x8 v; } ua, ub;
        ua.u[0] = cvtpk(s0[0], s0[1]); ua.u[1] = cvtpk(s0[2], s0[3]);
        ua.u[2] = cvtpk(s1[0], s1[1]); ua.u[3] = cvtpk(s1[2], s1[3]);
        ub.u[0] = cvtpk(s2[0], s2[1]); ub.u[1] = cvtpk(s2[2], s2[3]);
        ub.u[2] = cvtpk(s3[0], s3[1]); ub.u[3] = cvtpk(s3[2], s3[3]);
        bf16x8 a0 = ua.v, a1 = ub.v;
#pragma unroll
        for (int q = 0; q < 3; q++) {
            f32x4 x = __builtin_amdgcn_mfma_f32_16x16x32_bf16(wkf[q][0], a0, blf[q], 0, 0, 0);
            accX[q] = __builtin_amdgcn_mfma_f32_16x16x32_bf16(wkf[q][1], a1, x, 0, 0, 0);
        }
        if (w7) {
            f32x4 x = __builtin_amdgcn_mfma_f32_16x16x32_bf16(wkf[3][0], a0, blf[3], 0, 0, 0);
            accX[3] = __builtin_amdgcn_mfma_f32_16x16x32_bf16(wkf[3][1], a1, x, 0, 0, 0);
        }
    }
    // issue load of x(1)
    s0 = *(const f32x4*)(sp);
    s1 = *(const f32x4*)(sp + 4);
    s2 = *(const f32x4*)(sp + 32);
    s3 = *(const f32x4*)(sp + 36);
    sp += F_IN;

    lds_barrier();   // hl zeros visible (seq loads stay in flight)

#pragma unroll 2
    for (int t = 0; t < T_LEN; t++) {
        const bool notlast = (t < T_LEN - 1);
        const bool last = !notlast;

        // ---- read h(t-1) B-frags from buf[t&1] ----
        const unsigned short* hp = hl + ((t & 1) << 11) + lane * 8;
        bf16x8 hf0 = *(const bf16x8*)(hp);
        bf16x8 hf1 = *(const bf16x8*)(hp + 512);
        bf16x8 hf2 = *(const bf16x8*)(hp + 1024);
        bf16x8 hf3 = *(const bf16x8*)(hp + 1536);

        // cvt x(t+1) (overlaps h-frag read latency; waits vmcnt for step t-1's issue)
        bf16x8 a0n = {}, a1n = {};
        if (notlast) {
            union { unsigned u[4]; bf16x8 v; } ua, ub;
            ua.u[0] = cvtpk(s0[0], s0[1]); ua.u[1] = cvtpk(s0[2], s0[3]);
            ua.u[2] = cvtpk(s1[0], s1[1]); ua.u[3] = cvtpk(s1[2], s1[3]);
            ub.u[0] = cvtpk(s2[0], s2[1]); ub.u[1] = cvtpk(s2[2], s2[3]);
            ub.u[2] = cvtpk(s3[0], s3[1]); ub.u[3] = cvtpk(s3[2], s3[3]);
            a0n = ua.v; a1n = ub.v;
        }

        // ---- rr = accX + h(t-1)@Wr^T : per-lane gate quads land in rr[q] ----
        f32x4 rr[4];
        __builtin_amdgcn_s_setprio(1);
#pragma unroll
        for (int q = 0; q < 3; q++)
            rr[q] = __builtin_amdgcn_mfma_f32_16x16x32_bf16(wrf[q][0], hf0, accX[q], 0, 0, 0);
        if (w7)
            rr[3] = __builtin_amdgcn_mfma_f32_16x16x32_bf16(wrf[3][0], hf0, accX[3], 0, 0, 0);
#pragma unroll
        for (int q = 0; q < 3; q++)
            rr[q] = __builtin_amdgcn_mfma_f32_16x16x32_bf16(wrf[q][1], hf1, rr[q], 0, 0, 0);
        if (w7)
            rr[3] = __builtin_amdgcn_mfma_f32_16x16x32_bf16(wrf[3][1], hf1, rr[3], 0, 0, 0);
#pragma unroll
        for (int q = 0; q < 3; q++)
            rr[q] = __builtin_amdgcn_mfma_f32_16x16x32_bf16(wrf[q][2], hf2, rr[q], 0, 0, 0);
        if (w7)
            rr[3] = __builtin_amdgcn_mfma_f32_16x16x32_bf16(wrf[3][2], hf2, rr[3], 0, 0, 0);
#pragma unroll
        for (int q = 0; q < 3; q++)
            rr[q] = __builtin_amdgcn_mfma_f32_16x16x32_bf16(wrf[q][3], hf3, rr[q], 0, 0, 0);
        if (w7)
            rr[3] = __builtin_amdgcn_mfma_f32_16x16x32_bf16(wrf[3][3], hf3, rr[3], 0, 0, 0);
        __builtin_amdgcn_s_setprio(0);

        // prefetch x(t+2) (rides across the LDS barrier; waited at t+1's cvt)
        if (t < T_LEN - 2) {
            s0 = *(const f32x4*)(sp);
            s1 = *(const f32x4*)(sp + 4);
            s2 = *(const f32x4*)(sp + 32);
            s3 = *(const f32x4*)(sp + 36);
            sp += F_IN;
        }

        // ---- gates in registers; write h(t) bf16 to buf[(t+1)&1] ----
        unsigned short* hwp = hl + (((t + 1) & 1) << 11);

#define DOGATE(RRQ, CR, HO, HW) do {                                  \
            float _i = sigm2(RRQ[0]), _f = sigm2(RRQ[1]);             \
            float _g = fmaxf(RRQ[2], 0.0f), _o = sigm2(RRQ[3]);       \
            CR = _f * CR + _i * _g;                                   \
            float _h = _o * fmaxf(CR, 0.0f);                          \
            hwp[HO] = (unsigned short)cvtpk(_h, _h);                  \
            if (last) h32[HW] = _h;                                   \
        } while (0)

        DOGATE(rr[0], cr0, hoq[0], h32q[0]);
        DOGATE(rr[1], cr1, hoq[1], h32q[1]);
        DOGATE(rr[2], cr2, hoq[2], h32q[2]);
        if (w7) DOGATE(rr[3], cr3, hoq[3], h32q[3]);

        // ---- accX = bias + x(t+1)@Wk^T (MFMA pipe, overlaps gate VALU) ----
        if (notlast) {
#pragma unroll
            for (int q = 0; q < 3; q++) {
                f32x4 x = __builtin_amdgcn_mfma_f32_16x16x32_bf16(wkf[q][0], a0n, blf[q], 0, 0, 0);
                accX[q] = __builtin_amdgcn_mfma_f32_16x16x32_bf16(wkf[q][1], a1n, x, 0, 0, 0);
            }
            if (w7) {
                f32x4 x = __builtin_amdgcn_mfma_f32_16x16x32_bf16(wkf[3][0], a0n, blf[3], 0, 0, 0);
                accX[3] = __builtin_amdgcn_mfma_f32_16x16x32_bf16(wkf[3][1], a1n, x, 0, 0, 0);
            }
        }

        lds_barrier();   // h(t) visible; protects buf WAR; vmem stays in flight
    }

    // ---- epilogue: fp32 dense chain + softmax (ROWS=8) ----
    float* att  = (float*)smem;            // [8][136]
    float* catb = (float*)(smem + 4352);   // [8][204]
    float* x1b  = (float*)(smem + 10880);  // [8][100]
    float* x2b  = (float*)(smem + 14080);  // [8][50]
    float* lgb  = (float*)(smem + 15680);  // [8][10]

    if (tid < 256) {
        f32x4 v = ((const f32x4*)(attrs + (size_t)b0 * A_IN))[tid];
        int row = tid >> 5, c4 = tid & 31;
        *(f32x4*)(att + row * 136 + c4 * 4) = v;
    }
    __syncthreads();

#pragma unroll
    for (int k = 0; k < 2; k++) {
        int e = tid + 512 * k;
        if (e < ROWS * H) {
            int b = e & 7, j = e >> 3;
            float s = bd[j];
            for (int kk = 0; kk < A_IN; kk++) s += att[b * 136 + kk] * Wd[kk * H + j];
            catb[b * 204 + j] = fmaxf(s, 0.0f);
            catb[b * 204 + H + j] = h32[b * H + j];
        }
    }
    __syncthreads();

#pragma unroll
    for (int k = 0; k < 2; k++) {
        int e = tid + 512 * k;
        if (e < ROWS * H) {
            int b = e & 7, j = e >> 3;
            float s = b1[j];
            for (int kk = 0; kk < 200; kk++) s += catb[b * 204 + kk] * W1[kk * H + j];
            x1b[b * H + j] = fmaxf(s, 0.0f);
        }
    }
    __syncthreads();

    if (tid < ROWS * 50) {
        int b = tid & 7, j = tid >> 3;
        float s = b2[j];
        for (int kk = 0; kk < H; kk++) s += x1b[b * H + kk] * W2[kk * 50 + j];
        x2b[b * 50 + j] = fmaxf(s, 0.0f);
    }
    __syncthreads();

    if (tid < ROWS * OUT_N) {
        int b = tid / OUT_N, o = tid % OUT_N;
        float s = bc[o];
        for (int kk = 0; kk < 50; kk++) s += x2b[b * 50 + kk] * Wc[kk * OUT_N + o];
        lgb[b * OUT_N + o] = s;
    }
    __syncthreads();

    if (tid < ROWS) {
        int b = tid;
        float m = -1e30f, v[10];
#pragma unroll
        for (int o = 0; o < 10; o++) { v[o] = lgb[b * 10 + o]; m = fmaxf(m, v[o]); }
        float ssum = 0.0f;
#pragma unroll
        for (int o = 0; o < 10; o++) { v[o] = __expf(v[o] - m); ssum += v[o]; }
        float inv = 1.0f / ssum;
#pragma unroll
        for (int o = 0; o < 10; o++) out[(size_t)(b0 + b) * 10 + o] = v[o] * inv;
    }
}

extern "C" void kernel_launch(void* const* d_in, const int* in_sizes, int n_in,
                              void* d_out, int out_size, void* d_ws, size_t ws_size,
                              hipStream_t stream) {
    const float* attrs = (const float*)d_in[0];
    const float* seq   = (const float*)d_in[1];
    const float* Wd    = (const float*)d_in[2];
    const float* bd    = (const float*)d_in[3];
    const float* Wk    = (const float*)d_in[4];
    const float* Wr    = (const float*)d_in[5];
    const float* bl    = (const float*)d_in[6];
    const float* W1    = (const float*)d_in[7];
    const float* b1    = (const float*)d_in[8];
    const float* W2    = (const float*)d_in[9];
    const float* b2    = (const float*)d_in[10];
    const float* Wc    = (const float*)d_in[11];
    const float* bc    = (const float*)d_in[12];
    float* out = (float*)d_out;

    hipLaunchKernelGGL(traj_kernel, dim3(512), dim3(512), 0, stream,
                       attrs, seq, Wd, bd, Wk, Wr, bl, W1, b1, W2, b2, Wc, bc, out);
}

// Round 7
// 438.605 us; speedup vs baseline: 4.1256x; 1.0066x over previous
//
#include <hip/hip_runtime.h>
#include <hip/hip_bf16.h>

#define T_LEN 200
#define F_IN 64
#define A_IN 128
#define H 100
#define H4 400
#define OUT_N 10
#define ROWS 8

typedef __attribute__((ext_vector_type(8))) short bf16x8;
typedef __attribute__((ext_vector_type(4))) float f32x4;

#define NLOG2E -1.4426950408889634f

__device__ __forceinline__ unsigned short f2bf(float f) {
    union { float f; unsigned u; } v; v.f = f;
    unsigned r = v.u + 0x7FFFu + ((v.u >> 16) & 1u);
    return (unsigned short)(r >> 16);
}

__device__ __forceinline__ unsigned cvtpk(float lo, float hi) {
    unsigned r;
    asm("v_cvt_pk_bf16_f32 %0, %1, %2" : "=v"(r) : "v"(lo), "v"(hi));
    return r;
}

// sigmoid(z) where zp = -log2(e)*z came out of the MFMA (weights pre-scaled)
__device__ __forceinline__ float sigm2(float zp) {
    return __builtin_amdgcn_rcpf(1.0f + __builtin_amdgcn_exp2f(zp));
}

// LDS-only barrier: do NOT drain vmcnt (seq prefetch stays in flight)
__device__ __forceinline__ void lds_barrier() {
    asm volatile("s_waitcnt lgkmcnt(0)" ::: "memory");
    __builtin_amdgcn_s_barrier();
}

// h fragment slot for (batch b, hidden j): B-frag col=lane&15=b, k=lg*8+i
#define HOFF(b, j) ((((j) >> 5) * 64 + ((b) + 16 * (((j) >> 3) & 3))) * 8 + ((j) & 7))

extern "C" __global__ void __launch_bounds__(512, 2)
traj_kernel(const float* __restrict__ attrs, const float* __restrict__ seq,
            const float* __restrict__ Wd, const float* __restrict__ bd,
            const float* __restrict__ Wk, const float* __restrict__ Wr,
            const float* __restrict__ bl, const float* __restrict__ W1,
            const float* __restrict__ b1, const float* __restrict__ W2,
            const float* __restrict__ b2, const float* __restrict__ Wc,
            const float* __restrict__ bc, float* __restrict__ out)
{
    // LDS map (bytes), total 62592:
    //   [0, 51200)       wkl  Wk A-frags: tile*2048 + kt*1024 + lane*16 (wave-private)
    //   [51200, 59392)   hl   ushort[2][2048]  h bf16 B-frag double buffer
    //   [59392, 62592)   h32  float[8][100]    final h fp32
    // epilogue aliases (wkl dead after loop): att [8][136]@0, catb [8][204]@4352,
    //   x1b [8][100]@10880, x2b [8][50]@14080, lgb [8][10]@15680
    __shared__ __align__(16) char smem[62592];
    unsigned short* hl = (unsigned short*)(smem + 51200);
    float* h32 = (float*)(smem + 59392);

    const int tid = threadIdx.x;
    const int lane = tid & 63;
    const int w = tid >> 6;
    const int ln15 = lane & 15;
    const int lg = lane >> 4;
    const int b0 = blockIdx.x * ROWS;

    // output-dim tiles (Z^T rows): waves 0..6 own {3w..3w+2}; wave 7 owns {21..24}
    const int nt0 = 3 * w;
    const int ntc = (w == 7) ? 4 : 3;
    const bool w7 = (w == 7);

    // A-frag: lane holds row m=lane&15, k=(lane>>4)*8+i. Permuted row p=tile*16+m
    // -> original column c=(tile*4+(m>>2))+100*(m&3); D rows lg*4+r = gates i,f,g,o
    // of hidden j=tile*4+lg. Gates i,f,o pre-scaled by -log2(e).
    const int rw = ln15 & 3;
    const int qr = ln15 >> 2;
    const float gsc = (rw == 2) ? 1.0f : NLOG2E;

    // ---- Wk frags -> LDS (wave-private; written once, read every step) ----
#pragma unroll
    for (int q = 0; q < 4; q++) {
        if (q < ntc) {
            const int tile = nt0 + q;
            const int c = (tile * 4 + qr) + 100 * rw;
#pragma unroll
            for (int kt = 0; kt < 2; kt++) {
                bf16x8 f;
#pragma unroll
                for (int i = 0; i < 8; i++) {
                    int k = kt * 32 + lg * 8 + i;
                    f[i] = (short)f2bf(gsc * Wk[k * H4 + c]);
                }
                *(bf16x8*)(smem + tile * 2048 + kt * 1024 + lane * 16) = f;
            }
        }
    }

    // ---- Wr frags in registers, bias folded into spare K-row k==100 ----
    bf16x8 wrf[4][4];
#pragma unroll
    for (int q = 0; q < 4; q++) {
        const bool v = (q < ntc);
        const int tile = nt0 + q;
        const int c = v ? (tile * 4 + qr) + 100 * rw : 0;
#pragma unroll
        for (int kt = 0; kt < 4; kt++) {
            bf16x8 f;
#pragma unroll
            for (int i = 0; i < 8; i++) {
                int k = kt * 32 + lg * 8 + i;
                float x = 0.0f;
                if (v && k < H) x = gsc * Wr[k * H4 + c];
                if (v && k == H) x = gsc * bl[c];   // bias row (h slot k=100 pinned to 1)
                f[i] = (short)f2bf(x);
            }
            wrf[q][kt] = f;
        }
    }

    // gate destinations: batch b = ln15 (8..15 confined garbage), hidden j_q
    int hoq[4];
#pragma unroll
    for (int q = 0; q < 4; q++) {
        int j = (nt0 + q) * 4 + lg;
        if (j > 99) j = 99;  // inactive q only
        hoq[q] = HOFF(ln15, j);
    }
    float cr0 = 0.f, cr1 = 0.f, cr2 = 0.f, cr3 = 0.f;

    // zero both h buffers, then pin bias slot k=100 to bf16(1.0) in both
    for (int i = tid; i < 4096; i += 512) hl[i] = 0;
    __syncthreads();
    if (tid < 32) {
        int b = tid & 15, buf = tid >> 4;
        hl[buf * 2048 + 1536 + 8 * b + 4] = 0x3F80;  // (k=100, batch b) = 1.0
    }

    // ---- seq staging: lane = batch row ln15 (clamped), feats lg*8..+7, 32+lg*8..+7
    int brow = b0 + ln15; if (brow > 4095) brow = 4095;
    const float* sp = seq + (size_t)brow * (T_LEN * F_IN) + lg * 8;
    f32x4 s0 = *(const f32x4*)(sp);
    f32x4 s1 = *(const f32x4*)(sp + 4);
    f32x4 s2 = *(const f32x4*)(sp + 32);
    f32x4 s3 = *(const f32x4*)(sp + 36);
    sp += F_IN;

    // prologue: accX = x(0)@Wk^T  (C starts at 0; bias comes via Wr k=100)
    f32x4 accX[4];
    {
        union { unsigned u[4]; bf16x8 v; } ua, ub;
        ua.u[0] = cvtpk(s0[0], s0[1]); ua.u[1] = cvtpk(s0[2], s0[3]);
        ua.u[2] = cvtpk(s1[0], s1[1]); ua.u[3] = cvtpk(s1[2], s1[3]);
        ub.u[0] = cvtpk(s2[0], s2[1]); ub.u[1] = cvtpk(s2[2], s2[3]);
        ub.u[2] = cvtpk(s3[0], s3[1]); ub.u[3] = cvtpk(s3[2], s3[3]);
        bf16x8 a0 = ua.v, a1 = ub.v;
        const f32x4 zz = { 0.f, 0.f, 0.f, 0.f };
#pragma unroll
        for (int q = 0; q < 4; q++) {
            if (q < ntc) {
                const char* wkp = smem + (nt0 + q) * 2048 + lane * 16;
                bf16x8 wa = *(const bf16x8*)(wkp);
                bf16x8 wb = *(const bf16x8*)(wkp + 1024);
                f32x4 x = __builtin_amdgcn_mfma_f32_16x16x32_bf16(wa, a0, zz, 0, 0, 0);
                accX[q] = __builtin_amdgcn_mfma_f32_16x16x32_bf16(wb, a1, x, 0, 0, 0);
            }
        }
    }
    // issue load of x(1)
    s0 = *(const f32x4*)(sp);
    s1 = *(const f32x4*)(sp + 4);
    s2 = *(const f32x4*)(sp + 32);
    s3 = *(const f32x4*)(sp + 36);
    sp += F_IN;

    lds_barrier();   // hl zeros + bias pins visible (seq loads stay in flight)

    for (int t = 0; t < T_LEN; t++) {
        const bool notlast = (t < T_LEN - 1);
        const bool last = !notlast;

        // ---- read h(t-1) B-frags from buf[t&1] ----
        const unsigned short* hp = hl + ((t & 1) << 11) + lane * 8;
        bf16x8 hf0 = *(const bf16x8*)(hp);
        bf16x8 hf1 = *(const bf16x8*)(hp + 512);
        bf16x8 hf2 = *(const bf16x8*)(hp + 1024);
        bf16x8 hf3 = *(const bf16x8*)(hp + 1536);

        // cvt x(t+1) (overlaps h-frag read latency)
        bf16x8 a0n = {}, a1n = {};
        if (notlast) {
            union { unsigned u[4]; bf16x8 v; } ua, ub;
            ua.u[0] = cvtpk(s0[0], s0[1]); ua.u[1] = cvtpk(s0[2], s0[3]);
            ua.u[2] = cvtpk(s1[0], s1[1]); ua.u[3] = cvtpk(s1[2], s1[3]);
            ub.u[0] = cvtpk(s2[0], s2[1]); ub.u[1] = cvtpk(s2[2], s2[3]);
            ub.u[2] = cvtpk(s3[0], s3[1]); ub.u[3] = cvtpk(s3[2], s3[3]);
            a0n = ua.v; a1n = ub.v;
        }

        // ---- rr = accX + h(t-1)@Wr^T (+bias via k=100) ----
        f32x4 rr[4];
        __builtin_amdgcn_s_setprio(1);
#pragma unroll
        for (int q = 0; q < 3; q++)
            rr[q] = __builtin_amdgcn_mfma_f32_16x16x32_bf16(wrf[q][0], hf0, accX[q], 0, 0, 0);
        if (w7)
            rr[3] = __builtin_amdgcn_mfma_f32_16x16x32_bf16(wrf[3][0], hf0, accX[3], 0, 0, 0);
#pragma unroll
        for (int q = 0; q < 3; q++)
            rr[q] = __builtin_amdgcn_mfma_f32_16x16x32_bf16(wrf[q][1], hf1, rr[q], 0, 0, 0);
        if (w7)
            rr[3] = __builtin_amdgcn_mfma_f32_16x16x32_bf16(wrf[3][1], hf1, rr[3], 0, 0, 0);
#pragma unroll
        for (int q = 0; q < 3; q++)
            rr[q] = __builtin_amdgcn_mfma_f32_16x16x32_bf16(wrf[q][2], hf2, rr[q], 0, 0, 0);
        if (w7)
            rr[3] = __builtin_amdgcn_mfma_f32_16x16x32_bf16(wrf[3][2], hf2, rr[3], 0, 0, 0);
#pragma unroll
        for (int q = 0; q < 3; q++)
            rr[q] = __builtin_amdgcn_mfma_f32_16x16x32_bf16(wrf[q][3], hf3, rr[q], 0, 0, 0);
        if (w7)
            rr[3] = __builtin_amdgcn_mfma_f32_16x16x32_bf16(wrf[3][3], hf3, rr[3], 0, 0, 0);
        __builtin_amdgcn_s_setprio(0);

        // prefetch x(t+2) (rides across the LDS barrier)
        if (t < T_LEN - 2) {
            s0 = *(const f32x4*)(sp);
            s1 = *(const f32x4*)(sp + 4);
            s2 = *(const f32x4*)(sp + 32);
            s3 = *(const f32x4*)(sp + 36);
            sp += F_IN;
        }

        // ---- gates in registers; write h(t) bf16 to buf[(t+1)&1] ----
        unsigned short* hwp = hl + (((t + 1) & 1) << 11);

#define DOGATE(RRQ, CR, Q) do {                                        \
            float _i = sigm2(RRQ[0]), _f = sigm2(RRQ[1]);              \
            float _g = fmaxf(RRQ[2], 0.0f), _o = sigm2(RRQ[3]);        \
            CR = _f * CR + _i * _g;                                    \
            float _h = _o * fmaxf(CR, 0.0f);                           \
            hwp[hoq[Q]] = (unsigned short)cvtpk(_h, _h);               \
            if (last && ln15 < 8) h32[ln15 * H + (nt0 + (Q)) * 4 + lg] = _h; \
        } while (0)

        DOGATE(rr[0], cr0, 0);
        DOGATE(rr[1], cr1, 1);
        DOGATE(rr[2], cr2, 2);
        if (w7) DOGATE(rr[3], cr3, 3);

        // ---- accX = x(t+1)@Wk^T, Wk frags streamed from LDS (off critical path) ----
        if (notlast) {
            const f32x4 zz = { 0.f, 0.f, 0.f, 0.f };
#pragma unroll
            for (int q = 0; q < 4; q++) {
                if (q < ntc) {
                    const char* wkp = smem + (nt0 + q) * 2048 + lane * 16;
                    bf16x8 wa = *(const bf16x8*)(wkp);
                    bf16x8 wb = *(const bf16x8*)(wkp + 1024);
                    f32x4 x = __builtin_amdgcn_mfma_f32_16x16x32_bf16(wa, a0n, zz, 0, 0, 0);
                    accX[q] = __builtin_amdgcn_mfma_f32_16x16x32_bf16(wb, a1n, x, 0, 0, 0);
                }
            }
        }

        lds_barrier();   // h(t) visible; protects buf WAR; vmem stays in flight
    }

    // ---- epilogue: fp32 dense chain + softmax (ROWS=8) ----
    float* att  = (float*)smem;            // [8][136]
    float* catb = (float*)(smem + 4352);   // [8][204]
    float* x1b  = (float*)(smem + 10880);  // [8][100]
    float* x2b  = (float*)(smem + 14080);  // [8][50]
    float* lgb  = (float*)(smem + 15680);  // [8][10]

    if (tid < 256) {
        f32x4 v = ((const f32x4*)(attrs + (size_t)b0 * A_IN))[tid];
        int row = tid >> 5, c4 = tid & 31;
        *(f32x4*)(att + row * 136 + c4 * 4) = v;
    }
    __syncthreads();

#pragma unroll
    for (int k = 0; k < 2; k++) {
        int e = tid + 512 * k;
        if (e < ROWS * H) {
            int b = e & 7, j = e >> 3;
            float s = bd[j];
            for (int kk = 0; kk < A_IN; kk++) s += att[b * 136 + kk] * Wd[kk * H + j];
            catb[b * 204 + j] = fmaxf(s, 0.0f);
            catb[b * 204 + H + j] = h32[b * H + j];
        }
    }
    __syncthreads();

#pragma unroll
    for (int k = 0; k < 2; k++) {
        int e = tid + 512 * k;
        if (e < ROWS * H) {
            int b = e & 7, j = e >> 3;
            float s = b1[j];
            for (int kk = 0; kk < 200; kk++) s += catb[b * 204 + kk] * W1[kk * H + j];
            x1b[b * H + j] = fmaxf(s, 0.0f);
        }
    }
    __syncthreads();

    if (tid < ROWS * 50) {
        int b = tid & 7, j = tid >> 3;
        float s = b2[j];
        for (int kk = 0; kk < H; kk++) s += x1b[b * H + kk] * W2[kk * 50 + j];
        x2b[b * 50 + j] = fmaxf(s, 0.0f);
    }
    __syncthreads();

    if (tid < ROWS * OUT_N) {
        int b = tid / OUT_N, o = tid % OUT_N;
        float s = bc[o];
        for (int kk = 0; kk < 50; kk++) s += x2b[b * 50 + kk] * Wc[kk * OUT_N + o];
        lgb[b * OUT_N + o] = s;
    }
    __syncthreads();

    if (tid < ROWS) {
        int b = tid;
        float m = -1e30f, v[10];
#pragma unroll
        for (int o = 0; o < 10; o++) { v[o] = lgb[b * 10 + o]; m = fmaxf(m, v[o]); }
        float ssum = 0.0f;
#pragma unroll
        for (int o = 0; o < 10; o++) { v[o] = __expf(v[o] - m); ssum += v[o]; }
        float inv = 1.0f / ssum;
#pragma unroll
        for (int o = 0; o < 10; o++) out[(size_t)(b0 + b) * 10 + o] = v[o] * inv;
    }
}

extern "C" void kernel_launch(void* const* d_in, const int* in_sizes, int n_in,
                              void* d_out, int out_size, void* d_ws, size_t ws_size,
                              hipStream_t stream) {
    const float* attrs = (const float*)d_in[0];
    const float* seq   = (const float*)d_in[1];
    const float* Wd    = (const float*)d_in[2];
    const float* bd    = (const float*)d_in[3];
    const float* Wk    = (const float*)d_in[4];
    const float* Wr    = (const float*)d_in[5];
    const float* bl    = (const float*)d_in[6];
    const float* W1    = (const float*)d_in[7];
    const float* b1    = (const float*)d_in[8];
    const float* W2    = (const float*)d_in[9];
    const float* b2    = (const float*)d_in[10];
    const float* Wc    = (const float*)d_in[11];
    const float* bc    = (const float*)d_in[12];
    float* out = (float*)d_out;

    hipLaunchKernelGGL(traj_kernel, dim3(512), dim3(512), 0, stream,
                       attrs, seq, Wd, bd, Wk, Wr, bl, W1, b1, W2, b2, Wc, bc, out);
}

// Round 8
// 246.387 us; speedup vs baseline: 7.3441x; 1.7802x over previous
//
#include <hip/hip_runtime.h>
#include <hip/hip_bf16.h>

#define T_LEN 200
#define F_IN 64
#define A_IN 128
#define H 100
#define H4 400
#define OUT_N 10
#define ROWS 16

typedef __attribute__((ext_vector_type(8))) short bf16x8;
typedef __attribute__((ext_vector_type(4))) float f32x4;

#define NLOG2E -1.4426950408889634f

__device__ __forceinline__ unsigned short f2bf(float f) {
    union { float f; unsigned u; } v; v.f = f;
    unsigned r = v.u + 0x7FFFu + ((v.u >> 16) & 1u);
    return (unsigned short)(r >> 16);
}

__device__ __forceinline__ unsigned cvtpk(float lo, float hi) {
    unsigned r;
    asm("v_cvt_pk_bf16_f32 %0, %1, %2" : "=v"(r) : "v"(lo), "v"(hi));
    return r;
}

// sigmoid(z) where zp = -log2(e)*z came out of the MFMA (weights pre-scaled)
__device__ __forceinline__ float sigm2(float zp) {
    return __builtin_amdgcn_rcpf(1.0f + __builtin_amdgcn_exp2f(zp));
}

// LDS-only barrier: do NOT drain vmcnt (seq prefetch stays in flight)
__device__ __forceinline__ void lds_barrier() {
    asm volatile("s_waitcnt lgkmcnt(0)" ::: "memory");
    __builtin_amdgcn_s_barrier();
}

// h fragment slot for (batch b, hidden j): B-frag col=lane&15=b, k=lg*8+i
#define HOFF(b, j) ((((j) >> 5) * 64 + ((b) + 16 * (((j) >> 3) & 3))) * 8 + ((j) & 7))

extern "C" __global__ void __launch_bounds__(512, 2)
traj_kernel(const float* __restrict__ attrs, const float* __restrict__ seq,
            const float* __restrict__ Wd, const float* __restrict__ bd,
            const float* __restrict__ Wk, const float* __restrict__ Wr,
            const float* __restrict__ bl, const float* __restrict__ W1,
            const float* __restrict__ b1, const float* __restrict__ W2,
            const float* __restrict__ b2, const float* __restrict__ Wc,
            const float* __restrict__ bc, float* __restrict__ out)
{
    // LDS map (bytes), total 27648:
    //   [0, 8192)       hl   ushort[2][2048]  h bf16 B-frag double buffer
    //   [8192, 14592)   h32  float[16][100]   final h fp32
    //   [14592, 27392)  catb float[16][200]   (epilogue)
    // epilogue aliases (loop-dead): att [16][128]@0, x1b [16][100]@0,
    //   x2b [16][50]@8192 (h32 dead after catb), lgb [16][10]@11392
    __shared__ __align__(16) char smem[27648];
    unsigned short* hl = (unsigned short*)smem;
    float* h32 = (float*)(smem + 8192);

    const int tid = threadIdx.x;
    const int lane = tid & 63;
    const int w = tid >> 6;
    const int ln15 = lane & 15;
    const int lg = lane >> 4;
    const int b0 = blockIdx.x * ROWS;

    // output-dim tiles (Z^T rows): waves 0..6 own {3w..3w+2}; wave 7 owns {21..24}
    const int nt0 = 3 * w;
    const int ntc = (w == 7) ? 4 : 3;
    const bool w7 = (w == 7);

    // A-frag: lane holds row m=lane&15, k=(lane>>4)*8+i. Permuted row p=tile*16+m
    // -> original column c=(tile*4+(m>>2))+100*(m&3); D rows lg*4+r = gates i,f,g,o
    // of hidden j=tile*4+lg. Gates i,f,o pre-scaled by -log2(e) for exp2 sigmoid.
    const int rw = ln15 & 3;
    const int qr = ln15 >> 2;
    const float gsc = (rw == 2) ? 1.0f : NLOG2E;

    // ---- Wk frags in registers ----
    bf16x8 wkf[4][2];
#pragma unroll
    for (int q = 0; q < 4; q++) {
        const bool v = (q < ntc);
        const int c = v ? ((nt0 + q) * 4 + qr) + 100 * rw : 0;
#pragma unroll
        for (int kt = 0; kt < 2; kt++) {
            bf16x8 f;
#pragma unroll
            for (int i = 0; i < 8; i++) {
                int k = kt * 32 + lg * 8 + i;
                f[i] = (short)f2bf(v ? gsc * Wk[k * H4 + c] : 0.0f);
            }
            wkf[q][kt] = f;
        }
    }

    // ---- Wr frags in registers, bias folded into spare K-row k==100 ----
    bf16x8 wrf[4][4];
#pragma unroll
    for (int q = 0; q < 4; q++) {
        const bool v = (q < ntc);
        const int c = v ? ((nt0 + q) * 4 + qr) + 100 * rw : 0;
#pragma unroll
        for (int kt = 0; kt < 4; kt++) {
            bf16x8 f;
#pragma unroll
            for (int i = 0; i < 8; i++) {
                int k = kt * 32 + lg * 8 + i;
                float x = 0.0f;
                if (v && k < H) x = gsc * Wr[k * H4 + c];
                if (v && k == H) x = gsc * bl[c];   // bias row (h slot k=100 pinned to 1)
                f[i] = (short)f2bf(x);
            }
            wrf[q][kt] = f;
        }
    }

    // gate destinations: batch b = ln15, hidden j_q = (nt0+q)*4 + lg
    int hoq[4];
#pragma unroll
    for (int q = 0; q < 4; q++) {
        int j = (nt0 + q) * 4 + lg;
        if (j > 99) j = 99;  // inactive q only
        hoq[q] = HOFF(ln15, j);
    }
    float cr0 = 0.f, cr1 = 0.f, cr2 = 0.f, cr3 = 0.f;
    float hq0 = 0.f, hq1 = 0.f, hq2 = 0.f, hq3 = 0.f;  // persistent last-h

    // zero both h buffers, then pin bias slot k=100 to bf16(1.0) in both
    for (int i = tid; i < 4096; i += 512) hl[i] = 0;
    __syncthreads();
    if (tid < 32) {
        int b = tid & 15, buf = tid >> 4;
        hl[buf * 2048 + 1536 + 8 * b + 4] = 0x3F80;  // (k=100, batch b) = 1.0
    }

    // ---- seq staging: lane = batch row ln15, feats lg*8..+7 and 32+lg*8..+7 ----
    const float* sp = seq + (size_t)(b0 + ln15) * (T_LEN * F_IN) + lg * 8;
    f32x4 s0 = *(const f32x4*)(sp);
    f32x4 s1 = *(const f32x4*)(sp + 4);
    f32x4 s2 = *(const f32x4*)(sp + 32);
    f32x4 s3 = *(const f32x4*)(sp + 36);
    sp += F_IN;

    // prologue: accX = x(0)@Wk^T  (C=0; bias arrives via Wr k=100 each step)
    f32x4 accX[4];
    {
        union { unsigned u[4]; bf16x8 v; } ua, ub;
        ua.u[0] = cvtpk(s0[0], s0[1]); ua.u[1] = cvtpk(s0[2], s0[3]);
        ua.u[2] = cvtpk(s1[0], s1[1]); ua.u[3] = cvtpk(s1[2], s1[3]);
        ub.u[0] = cvtpk(s2[0], s2[1]); ub.u[1] = cvtpk(s2[2], s2[3]);
        ub.u[2] = cvtpk(s3[0], s3[1]); ub.u[3] = cvtpk(s3[2], s3[3]);
        bf16x8 a0 = ua.v, a1 = ub.v;
        const f32x4 zz = { 0.f, 0.f, 0.f, 0.f };
#pragma unroll
        for (int q = 0; q < 3; q++) {
            f32x4 x = __builtin_amdgcn_mfma_f32_16x16x32_bf16(wkf[q][0], a0, zz, 0, 0, 0);
            accX[q] = __builtin_amdgcn_mfma_f32_16x16x32_bf16(wkf[q][1], a1, x, 0, 0, 0);
        }
        if (w7) {
            f32x4 x = __builtin_amdgcn_mfma_f32_16x16x32_bf16(wkf[3][0], a0, zz, 0, 0, 0);
            accX[3] = __builtin_amdgcn_mfma_f32_16x16x32_bf16(wkf[3][1], a1, x, 0, 0, 0);
        }
    }
    // issue load of x(1)
    s0 = *(const f32x4*)(sp);
    s1 = *(const f32x4*)(sp + 4);
    s2 = *(const f32x4*)(sp + 32);
    s3 = *(const f32x4*)(sp + 36);
    sp += F_IN;

    lds_barrier();   // hl zeros + bias pins visible (seq loads stay in flight)

    for (int t = 0; t < T_LEN; t++) {
        const bool notlast = (t < T_LEN - 1);

        // ---- read h(t-1) B-frags from buf[t&1] ----
        const unsigned short* hp = hl + ((t & 1) << 11) + lane * 8;
        bf16x8 hf0 = *(const bf16x8*)(hp);
        bf16x8 hf1 = *(const bf16x8*)(hp + 512);
        bf16x8 hf2 = *(const bf16x8*)(hp + 1024);
        bf16x8 hf3 = *(const bf16x8*)(hp + 1536);

        // cvt x(t+1) (overlaps h-frag read latency)
        bf16x8 a0n = {}, a1n = {};
        if (notlast) {
            union { unsigned u[4]; bf16x8 v; } ua, ub;
            ua.u[0] = cvtpk(s0[0], s0[1]); ua.u[1] = cvtpk(s0[2], s0[3]);
            ua.u[2] = cvtpk(s1[0], s1[1]); ua.u[3] = cvtpk(s1[2], s1[3]);
            ub.u[0] = cvtpk(s2[0], s2[1]); ub.u[1] = cvtpk(s2[2], s2[3]);
            ub.u[2] = cvtpk(s3[0], s3[1]); ub.u[3] = cvtpk(s3[2], s3[3]);
            a0n = ua.v; a1n = ub.v;
        }

        // ---- rr = accX + h(t-1)@Wr^T (+bias via k=100) ----
        f32x4 rr[4];
        __builtin_amdgcn_s_setprio(1);
#pragma unroll
        for (int q = 0; q < 3; q++)
            rr[q] = __builtin_amdgcn_mfma_f32_16x16x32_bf16(wrf[q][0], hf0, accX[q], 0, 0, 0);
        if (w7)
            rr[3] = __builtin_amdgcn_mfma_f32_16x16x32_bf16(wrf[3][0], hf0, accX[3], 0, 0, 0);
#pragma unroll
        for (int q = 0; q < 3; q++)
            rr[q] = __builtin_amdgcn_mfma_f32_16x16x32_bf16(wrf[q][1], hf1, rr[q], 0, 0, 0);
        if (w7)
            rr[3] = __builtin_amdgcn_mfma_f32_16x16x32_bf16(wrf[3][1], hf1, rr[3], 0, 0, 0);
#pragma unroll
        for (int q = 0; q < 3; q++)
            rr[q] = __builtin_amdgcn_mfma_f32_16x16x32_bf16(wrf[q][2], hf2, rr[q], 0, 0, 0);
        if (w7)
            rr[3] = __builtin_amdgcn_mfma_f32_16x16x32_bf16(wrf[3][2], hf2, rr[3], 0, 0, 0);
#pragma unroll
        for (int q = 0; q < 3; q++)
            rr[q] = __builtin_amdgcn_mfma_f32_16x16x32_bf16(wrf[q][3], hf3, rr[q], 0, 0, 0);
        if (w7)
            rr[3] = __builtin_amdgcn_mfma_f32_16x16x32_bf16(wrf[3][3], hf3, rr[3], 0, 0, 0);
        __builtin_amdgcn_s_setprio(0);

        // prefetch x(t+2) (rides across the LDS barrier)
        if (t < T_LEN - 2) {
            s0 = *(const f32x4*)(sp);
            s1 = *(const f32x4*)(sp + 4);
            s2 = *(const f32x4*)(sp + 32);
            s3 = *(const f32x4*)(sp + 36);
            sp += F_IN;
        }

        // ---- gates in registers; write h(t) bf16 to buf[(t+1)&1] ----
        unsigned short* hwp = hl + (((t + 1) & 1) << 11);

#define DOGATE(RRQ, CR, HQ, Q) do {                                    \
            float _i = sigm2(RRQ[0]), _f = sigm2(RRQ[1]);              \
            float _g = fmaxf(RRQ[2], 0.0f), _o = sigm2(RRQ[3]);        \
            CR = _f * CR + _i * _g;                                    \
            float _h = _o * fmaxf(CR, 0.0f);                           \
            HQ = _h;                                                   \
            hwp[hoq[Q]] = (unsigned short)cvtpk(_h, _h);               \
        } while (0)

        DOGATE(rr[0], cr0, hq0, 0);
        DOGATE(rr[1], cr1, hq1, 1);
        DOGATE(rr[2], cr2, hq2, 2);
        if (w7) DOGATE(rr[3], cr3, hq3, 3);

        // ---- accX = x(t+1)@Wk^T (MFMA pipe, overlaps gate VALU) ----
        if (notlast) {
            const f32x4 zz = { 0.f, 0.f, 0.f, 0.f };
#pragma unroll
            for (int q = 0; q < 3; q++) {
                f32x4 x = __builtin_amdgcn_mfma_f32_16x16x32_bf16(wkf[q][0], a0n, zz, 0, 0, 0);
                accX[q] = __builtin_amdgcn_mfma_f32_16x16x32_bf16(wkf[q][1], a1n, x, 0, 0, 0);
            }
            if (w7) {
                f32x4 x = __builtin_amdgcn_mfma_f32_16x16x32_bf16(wkf[3][0], a0n, zz, 0, 0, 0);
                accX[3] = __builtin_amdgcn_mfma_f32_16x16x32_bf16(wkf[3][1], a1n, x, 0, 0, 0);
            }
        }

        lds_barrier();   // h(t) visible; protects buf WAR; vmem stays in flight
    }

    // ---- final h -> h32 (from persistent registers) ----
#pragma unroll
    for (int q = 0; q < 3; q++)
        h32[ln15 * H + (nt0 + q) * 4 + lg] = (q == 0) ? hq0 : (q == 1) ? hq1 : hq2;
    if (w7) h32[ln15 * H + 24 * 4 + lg] = hq3;

    // ---- epilogue: fp32 dense chain + softmax ----
    float* att  = (float*)smem;             // [16][128]
    float* catb = (float*)(smem + 14592);   // [16][200]
    float* x1b  = (float*)smem;             // [16][100]
    float* x2b  = (float*)(smem + 8192);    // [16][50]
    float* lgb  = (float*)(smem + 11392);   // [16][10]

    {
        const f32x4* src = (const f32x4*)(attrs + (size_t)b0 * A_IN);
        f32x4 v = src[tid];
        __syncthreads();                    // h32 writes + hl reads done; att overlays hl
        ((f32x4*)att)[tid] = v;             // 16x128 floats
    }
    __syncthreads();

#pragma unroll
    for (int k = 0; k < 4; k++) {
        int e = tid + 512 * k;
        if (e < ROWS * H) {
            int b = e & 15, j = e >> 4;
            float s = bd[j];
            for (int kk = 0; kk < A_IN; kk++) s += att[b * A_IN + kk] * Wd[kk * H + j];
            catb[b * 200 + j] = fmaxf(s, 0.0f);
            catb[b * 200 + H + j] = h32[b * H + j];
        }
    }
    __syncthreads();

#pragma unroll
    for (int k = 0; k < 4; k++) {
        int e = tid + 512 * k;
        if (e < ROWS * H) {
            int b = e & 15, j = e >> 4;
            float s = b1[j];
            for (int kk = 0; kk < 200; kk++) s += catb[b * 200 + kk] * W1[kk * H + j];
            x1b[b * H + j] = fmaxf(s, 0.0f);
        }
    }
    __syncthreads();

#pragma unroll
    for (int k = 0; k < 2; k++) {
        int e = tid + 512 * k;
        if (e < ROWS * 50) {
            int b = e & 15, j = e >> 4;
            float s = b2[j];
            for (int kk = 0; kk < H; kk++) s += x1b[b * H + kk] * W2[kk * 50 + j];
            x2b[b * 50 + j] = fmaxf(s, 0.0f);
        }
    }
    __syncthreads();

    if (tid < ROWS * OUT_N) {
        int b = tid / OUT_N, o = tid % OUT_N;
        float s = bc[o];
        for (int kk = 0; kk < 50; kk++) s += x2b[b * 50 + kk] * Wc[kk * OUT_N + o];
        lgb[b * OUT_N + o] = s;
    }
    __syncthreads();

    if (tid < ROWS) {
        int b = tid;
        float m = -1e30f, v[10];
#pragma unroll
        for (int o = 0; o < 10; o++) { v[o] = lgb[b * 10 + o]; m = fmaxf(m, v[o]); }
        float ssum = 0.0f;
#pragma unroll
        for (int o = 0; o < 10; o++) { v[o] = __expf(v[o] - m); ssum += v[o]; }
        float inv = 1.0f / ssum;
#pragma unroll
        for (int o = 0; o < 10; o++) out[(size_t)(b0 + b) * 10 + o] = v[o] * inv;
    }
}

extern "C" void kernel_launch(void* const* d_in, const int* in_sizes, int n_in,
                              void* d_out, int out_size, void* d_ws, size_t ws_size,
                              hipStream_t stream) {
    const float* attrs = (const float*)d_in[0];
    const float* seq   = (const float*)d_in[1];
    const float* Wd    = (const float*)d_in[2];
    const float* bd    = (const float*)d_in[3];
    const float* Wk    = (const float*)d_in[4];
    const float* Wr    = (const float*)d_in[5];
    const float* bl    = (const float*)d_in[6];
    const float* W1    = (const float*)d_in[7];
    const float* b1    = (const float*)d_in[8];
    const float* W2    = (const float*)d_in[9];
    const float* b2    = (const float*)d_in[10];
    const float* Wc    = (const float*)d_in[11];
    const float* bc    = (const float*)d_in[12];
    float* out = (float*)d_out;

    hipLaunchKernelGGL(traj_kernel, dim3(256), dim3(512), 0, stream,
                       attrs, seq, Wd, bd, Wk, Wr, bl, W1, b1, W2, b2, Wc, bc, out);
}